// Round 10
// baseline (304.938 us; speedup 1.0000x reference)
//
#include <hip/hip_runtime.h>
#include <hip/hip_bf16.h>
#include <stdint.h>

// Problem constants: B=8, S=2048, D_IN=4096, D_OUT=4096
#define MROWS 16384
#define DIN   4096
#define DOUT  4096
#define KEFF  1024

typedef __attribute__((ext_vector_type(8))) __bf16 bf16x8;
typedef __attribute__((ext_vector_type(4))) float f32x4;

#define AS1 __attribute__((address_space(1)))
#define AS3 __attribute__((address_space(3)))

__device__ __forceinline__ uint32_t f2bf_rne(float f) {
  union { float f; uint32_t u; } v; v.f = f;
  uint32_t u = v.u;
  return (u + 0x7fffu + ((u >> 16) & 1u)) >> 16;
}

// Merged gather: 2-of-8 (positions 0,2 per group of 8) for x then w.
__global__ void venom_gather_all(const float* __restrict__ x,
                                 const float* __restrict__ w,
                                 uint2* __restrict__ xg, uint2* __restrict__ wg) {
  const int PX = MROWS * (DIN / 16);
  const int PW = DOUT * (DIN / 16);
  int stride = gridDim.x * blockDim.x;
  for (int i = blockIdx.x * blockDim.x + threadIdx.x; i < PX + PW; i += stride) {
    const float* src; uint2* dst; int idx;
    if (i < PX) { src = x; dst = xg; idx = i; }
    else        { src = w; dst = wg; idx = i - PX; }
    const float4* p = reinterpret_cast<const float4*>(src) + (size_t)idx * 4;
    float4 a = p[0];
    float4 b = p[2];
    uint2 r;
    r.x = f2bf_rne(a.x) | (f2bf_rne(a.z) << 16);
    r.y = f2bf_rne(b.x) | (f2bf_rne(b.z) << 16);
    dst[idx] = r;
  }
}

// ---- persistent 128x128 bf16 GEMM, 2 independent blocks/CU (64 KiB LDS) ----
// A = Xg [MROWS][KEFF] bf16 row-major, B = Wg [DOUT][KEFF] bf16 row-major (B^T).
// C[m][n] = sum_k A[m][k]*B[n][k] + bias[n], fp32 row-major.
// Block: 256 thr (4 waves, 2x2), fixed nblk, 8 consecutive mblk tiles.
#define BM 128
#define BN 128
#define BK 64
#define NT (KEFF / BK)   // 16
#define TPB 8            // output tiles (mblk steps) per block
#define LTOT (NT * TPB)  // 128

// LDS k-half: [64 superrows][128B]; superrow sr = rows 2sr,2sr+1 (32 k = 64B
// each), 8x16B slots XOR-swizzled by (sr&7). 8 KB per [buf][kh].
__device__ __forceinline__ int swz_off(int R, int lg) {
  int sr = R >> 1;
  return sr * 128 + (((((R & 1) << 2) | lg) ^ (sr & 7)) << 4);
}

#define WAIT_VM(n) asm volatile("s_waitcnt vmcnt(" #n ")" ::: "memory")
#define BAR() __builtin_amdgcn_s_barrier()

__global__ __launch_bounds__(256, 2) void venom_gemm_2c(
    const __bf16* __restrict__ A, const __bf16* __restrict__ Bm,
    const float* __restrict__ bias, float* __restrict__ C) {
  // [buf][kh][128 rows x 32 k] for A and B: 2*2*8KB*2 = 64 KiB -> 2 blocks/CU
  __shared__ __bf16 As[2][2][128 * 32];
  __shared__ __bf16 Bs[2][2][128 * 32];

  // grid = 512; XCD-bijective swizzle (512 % 8 == 0)
  int nwg = gridDim.x;
  int cpx = nwg >> 3;
  int bid = blockIdx.x;
  int swz = (bid & 7) * cpx + (bid >> 3);
  int nblk = swz & 31;   // fixed output-column block (32 nblk of 128)
  int mgrp = swz >> 5;   // 0..15; tile j -> mblk = mgrp*8 + j

  int t = threadIdx.x;
  int wid = t >> 6, l = t & 63;
  int wr = wid >> 1, wc = wid & 1;   // 2x2 wave grid; wave owns 64x64 of C
  int lr = l & 15, lg = l >> 4;

  const __bf16* Bg = Bm + (size_t)(nblk * BN) * KEFF;

  float biasr[4];
  #pragma unroll
  for (int ni = 0; ni < 4; ++ni)
    biasr[ni] = bias[nblk * BN + wc * 64 + ni * 16 + lr];

  f32x4 acc[4][4] = {};

  // Stage ONE k-half of global iteration L2: {A-half + B-half} together,
  // 4 loads/thread (R4's proven invariant: vm(4) drains exactly one half-pair).
  // Linear LDS dest, inverse-swizzled global source (rule #21).
  auto stage_half = [&](int L2, int kh) {
    const int buf = L2 & 1;
    const int k0 = (L2 & (NT - 1)) * BK + kh * 32;
    const __bf16* Ag = A + (size_t)((mgrp * TPB + (L2 >> 4)) * BM) * KEFF;
    #pragma unroll
    for (int i = 0; i < 2; ++i) {
      int e = i * 256 + t;        // 16B chunk 0..511 within the half
      int sr = e >> 3;
      int s = (e & 7) ^ (sr & 7);
      int row = sr * 2 + (s >> 2);
      int koff = (s & 3) * 8;
      __builtin_amdgcn_global_load_lds(
          (const AS1 uint32_t*)(Ag + (size_t)row * KEFF + k0 + koff),
          ((AS3 uint32_t*)&As[buf][kh][0]) + e * 4, 16, 0, 0);
      __builtin_amdgcn_global_load_lds(
          (const AS1 uint32_t*)(Bg + (size_t)row * KEFF + k0 + koff),
          ((AS3 uint32_t*)&Bs[buf][kh][0]) + e * 4, 16, 0, 0);
    }
  };

  // Prologue: both halves of iteration 0 in flight (8 loads).
  stage_half(0, 0);
  stage_half(0, 1);

  #pragma unroll 1
  for (int j = 0; j < TPB; ++j) {
    #pragma unroll 1
    for (int kt = 0; kt < NT; ++kt) {
      const int L = j * NT + kt;
      const int cur = L & 1;
      const bool more = (L + 1 < LTOT);

      // ---- ph0 (kh=0): vm(4) drains h(L,0); h(L,1) stays in flight ----
      WAIT_VM(4);
      BAR();
      {
        const char* aB = (const char*)&As[cur][0][0];
        const char* bB = (const char*)&Bs[cur][0][0];
        bf16x8 af[4], bf[4];
        #pragma unroll
        for (int mi = 0; mi < 4; ++mi)
          af[mi] = *(const bf16x8*)(aB + swz_off(wr * 64 + mi * 16 + lr, lg));
        #pragma unroll
        for (int ni = 0; ni < 4; ++ni)
          bf[ni] = *(const bf16x8*)(bB + swz_off(wc * 64 + ni * 16 + lr, lg));
        if (more) stage_half(L + 1, 0);
        __builtin_amdgcn_s_setprio(1);
        #pragma unroll
        for (int mi = 0; mi < 4; ++mi)
          #pragma unroll
          for (int ni = 0; ni < 4; ++ni)
            acc[mi][ni] = __builtin_amdgcn_mfma_f32_16x16x32_bf16(
                af[mi], bf[ni], acc[mi][ni], 0, 0, 0);
        __builtin_amdgcn_s_setprio(0);
      }

      // ---- ph1 (kh=1): vm(4) drains h(L,1); h(L+1,0) stays in flight ----
      if (more) WAIT_VM(4);
      else      WAIT_VM(0);
      BAR();
      {
        const char* aB = (const char*)&As[cur][1][0];
        const char* bB = (const char*)&Bs[cur][1][0];
        bf16x8 af[4], bf[4];
        #pragma unroll
        for (int mi = 0; mi < 4; ++mi)
          af[mi] = *(const bf16x8*)(aB + swz_off(wr * 64 + mi * 16 + lr, lg));
        #pragma unroll
        for (int ni = 0; ni < 4; ++ni)
          bf[ni] = *(const bf16x8*)(bB + swz_off(wc * 64 + ni * 16 + lr, lg));
        if (more) stage_half(L + 1, 1);
        __builtin_amdgcn_s_setprio(1);
        #pragma unroll
        for (int mi = 0; mi < 4; ++mi)
          #pragma unroll
          for (int ni = 0; ni < 4; ++ni)
            acc[mi][ni] = __builtin_amdgcn_mfma_f32_16x16x32_bf16(
                af[mi], bf[ni], acc[mi][ni], 0, 0, 0);
        __builtin_amdgcn_s_setprio(0);
      }
    }

    // Epilogue for tile j (stores only; overlaps the in-flight staging).
    {
      int colbase = nblk * BN + wc * 64;
      int rowbase = (mgrp * TPB + j) * BM + wr * 64;
      #pragma unroll
      for (int mi = 0; mi < 4; ++mi) {
        int row0 = rowbase + mi * 16 + lg * 4;
        #pragma unroll
        for (int ni = 0; ni < 4; ++ni) {
          int col = colbase + ni * 16 + lr;
          f32x4 cv = acc[mi][ni];
          #pragma unroll
          for (int jj = 0; jj < 4; ++jj)
            C[(size_t)(row0 + jj) * DOUT + col] = cv[jj] + biasr[ni];
          acc[mi][ni] = (f32x4){0.f, 0.f, 0.f, 0.f};
        }
      }
    }
  }
}

// Fallback
__global__ void venom_naive(const float* __restrict__ x, const float* __restrict__ w,
                            const float* __restrict__ bias, float* __restrict__ out) {
  size_t total = (size_t)MROWS * DOUT;
  size_t stride = (size_t)gridDim.x * blockDim.x;
  for (size_t idx = (size_t)blockIdx.x * blockDim.x + threadIdx.x; idx < total;
       idx += stride) {
    int m = (int)(idx / DOUT), n = (int)(idx % DOUT);
    const float* xr = x + (size_t)m * DIN;
    const float* wr = w + (size_t)n * DIN;
    float s = 0.f;
    for (int g = 0; g < DIN / 8; ++g)
      s += xr[g * 8] * wr[g * 8] + xr[g * 8 + 2] * wr[g * 8 + 2];
    out[idx] = s + bias[n];
  }
}

extern "C" void kernel_launch(void* const* d_in, const int* in_sizes, int n_in,
                              void* d_out, int out_size, void* d_ws, size_t ws_size,
                              hipStream_t stream) {
  const float* x    = (const float*)d_in[0];
  const float* wgt  = (const float*)d_in[1];
  const float* bias = (const float*)d_in[2];
  float* out = (float*)d_out;

  const size_t xg_bytes = (size_t)MROWS * KEFF * 2;
  const size_t wg_bytes = (size_t)DOUT * KEFF * 2;

  if (ws_size < xg_bytes + wg_bytes) {
    venom_naive<<<2048, 256, 0, stream>>>(x, wgt, bias, out);
    return;
  }

  uint32_t* xg = (uint32_t*)d_ws;
  uint32_t* wg = (uint32_t*)((char*)d_ws + xg_bytes);

  venom_gather_all<<<2048, 256, 0, stream>>>(x, wgt, (uint2*)xg, (uint2*)wg);

  // 512 blocks = 2 independent blocks per CU (64 KiB LDS each).
  venom_gemm_2c<<<(MROWS / BM / TPB) * (DOUT / BN), 256, 0, stream>>>(
      (const __bf16*)xg, (const __bf16*)wg, bias, out);
}